// Round 15
// baseline (316.980 us; speedup 1.0000x reference)
//
#include <hip/hip_runtime.h>
#include <hip/hip_bf16.h>

constexpr int kC   = 2048;
constexpr int kNS  = 5;
constexpr int kNQ  = 25;
constexpr int kPER = 30;
constexpr int kD   = 64;
constexpr int kS   = 32;
constexpr int kQ   = kC * kNQ;              // 51200
constexpr int kSplit = 8;
constexpr int kSubt  = (kC / kSplit) / 16;  // 16 subtiles per task
constexpr int kCPS   = kC / kSplit;         // 256 classes per split
constexpr int kTPS   = kQ / 32;             // 1600 query tiles (32 q each)
constexpr int kBlkPerSplit = kTPS / 8;      // 200 blocks per split (8 waves/block)

constexpr float kLOG2E = 1.44269504088896340736f;
constexpr float kC2    = kLOG2E * kLOG2E;
constexpr float kNEG2C = -2.0f * kC2;
constexpr float kBIG   = 1e30f;

// Workspace (float offsets), ~4.7 MB total.
constexpr size_t OP_PROT = 0;                              // [C*D] f32 protos
constexpr size_t OP_PSWZ = OP_PROT + (size_t)kC * kD;      // [C*D bf16] swizzled frags, scaled by -2*c2
constexpr size_t OP_PN   = OP_PSWZ + (size_t)kC * kD / 2;  // [C] |p|^2 raw
constexpr size_t OP_PNC2 = OP_PN + kC;                     // [C] |p|^2 * kC2
constexpr size_t OP_SSWH = OP_PNC2 + kC;                   // [S*D bf16] sector frags hi
constexpr size_t OP_SSWL = OP_SSWH + (size_t)kS * kD / 2;  // [S*D bf16] sector frags lo
constexpr size_t OP_SN   = OP_SSWL + (size_t)kS * kD / 2;  // [S] |s|^2
constexpr size_t OP_QNC  = OP_SN + kS;                     // [Q] qn * kC2
constexpr size_t OP_QSEC = OP_QNC + kQ;                    // [Q] int query sector
constexpr size_t OP_DT   = OP_QSEC + kQ;                   // [Q] exact fp32 dtrue
constexpr size_t OP_TC   = OP_DT + kQ;                     // [Q] int true class
constexpr size_t OP_S2   = OP_TC + kQ;                     // [Split*Q] partial sum exp
constexpr size_t OP_PB   = OP_S2 + (size_t)kSplit * kQ;    // [Split*Q] uint argmin keys
constexpr size_t OP_ACC  = OP_PB + (size_t)kSplit * kQ;    // [2]
constexpr size_t OP_TICK = OP_ACC + 2;                     // [1] int global merge ticket
constexpr size_t OP_QTK  = OP_TICK + 1;                    // [kTPS] int per-tile tickets

typedef __attribute__((ext_vector_type(8))) short short8;
typedef __attribute__((ext_vector_type(4))) float f32x4;

__device__ inline ushort f2bf(float f) {
    __hip_bfloat16 h = __float2bfloat16(f);
    return *reinterpret_cast<ushort*>(&h);
}
__device__ inline float bf2f(ushort u) {
    uint v = ((uint)u) << 16;
    return __int_as_float((int)v);
}
__device__ inline short8 pack_hi(float4 a, float4 b) {
    short8 r;
    r[0] = (short)f2bf(a.x); r[1] = (short)f2bf(a.y);
    r[2] = (short)f2bf(a.z); r[3] = (short)f2bf(a.w);
    r[4] = (short)f2bf(b.x); r[5] = (short)f2bf(b.y);
    r[6] = (short)f2bf(b.z); r[7] = (short)f2bf(b.w);
    return r;
}
__device__ inline void packhl(float4 a, float4 b, short8& hi, short8& lo) {
    float v[8] = {a.x, a.y, a.z, a.w, b.x, b.y, b.z, b.w};
#pragma unroll
    for (int i = 0; i < 8; ++i) {
        ushort h = f2bf(v[i]);
        hi[i] = (short)h;
        lo[i] = (short)f2bf(v[i] - bf2f(h));
    }
}

// K1: fused prep (verified absmax 0.0). Blocks [0,512): class protos
// (4 classes/block): f32 proto + swizzled bf16 frag scaled by -2*c2 + |p|^2
// (+ zero accumulators). Blocks [512,544): sector protos read x directly
// (csec[c]=c%32 episode structure); block 512 also zeroes the tile tickets.
__global__ __launch_bounds__(256) void k_prepsec(const float* __restrict__ x,
                                                 float* __restrict__ ws) {
    int t = threadIdx.x;
    if (blockIdx.x < 512) {
        int c = blockIdx.x * 4 + (t >> 6);
        int d = t & 63;
        const float* base = x + (size_t)c * kPER * kD + d;
        float p = 0.f;
#pragma unroll
        for (int s = 0; s < kNS; ++s) p += base[s * kD];
        p *= (1.f / kNS);
        ws[OP_PROT + (size_t)c * kD + d] = p;
        ((ushort*)(ws + OP_PSWZ))[((c >> 4) * 1024) + ((d >> 3) * 128) + ((c & 15) * 8) + (d & 7)] =
            f2bf(p * kNEG2C);
        float sq = p * p;
        for (int off = 32; off; off >>= 1) sq += __shfl_down(sq, off);
        if (d == 0) {
            ws[OP_PN + c] = sq;
            ws[OP_PNC2 + c] = sq * kC2;
        }
        if (blockIdx.x == 0 && t == 0) {
            ws[OP_ACC] = 0.f;
            ws[OP_ACC + 1] = 0.f;
            ((int*)ws)[OP_TICK] = 0;
        }
    } else {
        __shared__ float sAcc[4][kD];
        int s = blockIdx.x - 512;
        int w = t >> 6, d = t & 63;
        if (s == 0) {
            for (int i = t; i < kTPS; i += 256) ((int*)ws)[OP_QTK + i] = 0;
        }
        float acc = 0.f;
#pragma unroll
        for (int j = 0; j < 16; ++j) {
            int c = s + 32 * (w + 4 * j);
            const float* base = x + (size_t)c * kPER * kD + d;
            float p = 0.f;
#pragma unroll
            for (int i = 0; i < kNS; ++i) p += base[i * kD];
            p *= (1.f / kNS);
            acc += p;
        }
        sAcc[w][d] = acc;
        __syncthreads();
        if (w == 0) {
            float sp = (sAcc[0][d] + sAcc[1][d] + sAcc[2][d] + sAcc[3][d]) * (1.f / 64.f);
            ushort h = f2bf(sp);
            ushort l = f2bf(sp - bf2f(h));
            int idx = ((s >> 4) * 1024) + ((d >> 3) * 128) + ((s & 15) * 8) + (d & 7);
            ((ushort*)(ws + OP_SSWH))[idx] = h;
            ((ushort*)(ws + OP_SSWL))[idx] = l;
            float sq = sp * sp;
            for (int off = 32; off; off >>= 1) sq += __shfl_down(sq, off);
            if (d == 0) ws[OP_SN + s] = sq;
        }
    }
}

// K2: per-query qn*kC2, sector assignment (double-bf16 MFMA), exact fp32 dtrue, tc.
// Kept separate from k_main (merging under a min-waves pin spilled in R13).
__global__ __launch_bounds__(256) void k_qprep(const float* __restrict__ x,
                                               const int* __restrict__ target,
                                               float* __restrict__ ws) {
    int t = threadIdx.x;
    int w = t >> 6, lane = t & 63;
    int lrow = lane & 15, lgr = lane >> 4;
    int qt = blockIdx.x * 4 + w;
    int q = qt * 16 + lrow;
    int row = (q / kNQ) * kPER + kNS + q % kNQ;
    const float* qr = x + (size_t)row * kD + lgr * 8;
    float4 qa0 = *(const float4*)qr,        qa1 = *(const float4*)(qr + 4);
    float4 qb0 = *(const float4*)(qr + 32), qb1 = *(const float4*)(qr + 36);

    float qn = qa0.x*qa0.x + qa0.y*qa0.y + qa0.z*qa0.z + qa0.w*qa0.w
             + qa1.x*qa1.x + qa1.y*qa1.y + qa1.z*qa1.z + qa1.w*qa1.w
             + qb0.x*qb0.x + qb0.y*qb0.y + qb0.z*qb0.z + qb0.w*qb0.w
             + qb1.x*qb1.x + qb1.y*qb1.y + qb1.z*qb1.z + qb1.w*qb1.w;
    qn += __shfl_xor(qn, 16);
    qn += __shfl_xor(qn, 32);

    int tc = target[row];
    const float* pr = ws + OP_PROT + (size_t)tc * kD + lgr * 8;
    float4 p00 = *(const float4*)pr,        p01 = *(const float4*)(pr + 4);
    float4 p10 = *(const float4*)(pr + 32), p11 = *(const float4*)(pr + 36);
    float dot = qa0.x*p00.x + qa0.y*p00.y + qa0.z*p00.z + qa0.w*p00.w
              + qa1.x*p01.x + qa1.y*p01.y + qa1.z*p01.z + qa1.w*p01.w
              + qb0.x*p10.x + qb0.y*p10.y + qb0.z*p10.z + qb0.w*p10.w
              + qb1.x*p11.x + qb1.y*p11.y + qb1.z*p11.z + qb1.w*p11.w;
    dot += __shfl_xor(dot, 16);
    dot += __shfl_xor(dot, 32);
    float dtrue = sqrtf(fmaxf(qn + ws[OP_PN + tc] - 2.f * dot, 0.f));

    short8 b0h, b0l, b1h, b1l;
    packhl(qa0, qa1, b0h, b0l);
    packhl(qb0, qb1, b1h, b1l);

    const ushort* ssh = (const ushort*)(ws + OP_SSWH);
    const ushort* ssl = (const ushort*)(ws + OP_SSWL);
    float bestS = INFINITY;
    int qsec = 0;
#pragma unroll
    for (int st = 0; st < 2; ++st) {
        short8 sh0 = *(const short8*)(ssh + st * 1024 + lane * 8);
        short8 sh1 = *(const short8*)(ssh + st * 1024 + 512 + lane * 8);
        short8 sl0 = *(const short8*)(ssl + st * 1024 + lane * 8);
        short8 sl1 = *(const short8*)(ssl + st * 1024 + 512 + lane * 8);
        f32x4 dh = {0.f, 0.f, 0.f, 0.f};
        dh = __builtin_amdgcn_mfma_f32_16x16x32_bf16(sh0, b0h, dh, 0, 0, 0);
        dh = __builtin_amdgcn_mfma_f32_16x16x32_bf16(sh1, b1h, dh, 0, 0, 0);
        dh = __builtin_amdgcn_mfma_f32_16x16x32_bf16(sh0, b0l, dh, 0, 0, 0);
        dh = __builtin_amdgcn_mfma_f32_16x16x32_bf16(sh1, b1l, dh, 0, 0, 0);
        dh = __builtin_amdgcn_mfma_f32_16x16x32_bf16(sl0, b0h, dh, 0, 0, 0);
        dh = __builtin_amdgcn_mfma_f32_16x16x32_bf16(sl1, b1h, dh, 0, 0, 0);
        f32x4 sn4 = *(const f32x4*)(ws + OP_SN + st * 16 + lgr * 4);
#pragma unroll
        for (int r2 = 0; r2 < 4; ++r2) {
            float score = fmaf(dh[r2], -2.f, sn4[r2]);
            int idx = st * 16 + lgr * 4 + r2;
            if (score < bestS) { bestS = score; qsec = idx; }
        }
    }
#pragma unroll
    for (int off = 16; off <= 32; off <<= 1) {
        float ob = __shfl_xor(bestS, off);
        int oi = __shfl_xor(qsec, off);
        if (ob < bestS || (ob == bestS && oi < qsec)) { bestS = ob; qsec = oi; }
    }
    if (lane < 16) {
        ws[OP_QNC + q] = qn * kC2;
        ((int*)ws)[OP_QSEC + q] = qsec;
        ws[OP_DT + q] = dtrue;
        ((int*)ws)[OP_TC + q] = tc;
    }
}

// K3: hot kernel + fused finalize. Per-tile ticket: the 8th split-wave to
// finish a query tile merges the partials (qsec already in registers),
// accumulates loss/acc, and the last merge-wave writes out[].
__global__ __launch_bounds__(512) void k_main(const float* __restrict__ x,
                                              float* __restrict__ ws,
                                              float* __restrict__ out) {
    __shared__ ushort sP[kSubt * 1024 + 1024];  // 34KB + pad for prefetch overrun
    __shared__ float sPn[kSubt * 16 + 16];

    int t = threadIdx.x;
    int w = t >> 6, lane = t & 63;
    int lrow = lane & 15, lgr = lane >> 4;
    int split = blockIdx.x / kBlkPerSplit;          // 8 waves share this split
    int qt = (blockIdx.x % kBlkPerSplit) * 8 + w;
    int qbase = qt * 32;
    int q1 = qbase + lrow, q2 = qbase + 16 + lrow;

    // Stage protos: 2048 float4 = 32KB, 4 per thread, coalesced.
    {
        const float4* gsrc = (const float4*)((const ushort*)(ws + OP_PSWZ) + (size_t)split * kSubt * 1024);
        float4* ldst = (float4*)sP;
#pragma unroll
        for (int j = 0; j < 4; ++j) ldst[t + j * 512] = gsrc[t + j * 512];
        if (t < kCPS) sPn[t] = ws[OP_PNC2 + split * kCPS + t];
    }

    int row1 = (q1 / kNQ) * kPER + kNS + q1 % kNQ;
    int row2 = (q2 / kNQ) * kPER + kNS + q2 % kNQ;
    const float* qr1 = x + (size_t)row1 * kD + lgr * 8;
    const float* qr2 = x + (size_t)row2 * kD + lgr * 8;
    float4 a10 = *(const float4*)qr1,        a11 = *(const float4*)(qr1 + 4);
    float4 a12 = *(const float4*)(qr1 + 32), a13 = *(const float4*)(qr1 + 36);
    float4 a20 = *(const float4*)qr2,        a21 = *(const float4*)(qr2 + 4);
    float4 a22 = *(const float4*)(qr2 + 32), a23 = *(const float4*)(qr2 + 36);
    short8 b0h1 = pack_hi(a10, a11), b1h1 = pack_hi(a12, a13);
    short8 b0h2 = pack_hi(a20, a21), b1h2 = pack_hi(a22, a23);

    float qn1 = ws[OP_QNC + q1];          // pre-scaled by kC2
    float qn2 = ws[OP_QNC + q2];
    int qsec1 = ((const int*)ws)[OP_QSEC + q1];
    int qsec2 = ((const int*)ws)[OP_QSEC + q2];

    bool m1a = (qsec1 & 1), m1b = (qsec1 >> 1) & 1, p1 = (qsec1 >> 4) & 1;
    float actb1 = (((qsec1 & 15) >> 2) == lgr) ? 0.f : kBIG;
    bool m2a = (qsec2 & 1), m2b = (qsec2 >> 1) & 1, p2 = (qsec2 >> 4) & 1;
    float actb2 = (((qsec2 & 15) >> 2) == lgr) ? 0.f : kBIG;

    float S0 = 0.f, S1 = 0.f, S2 = 0.f, S3 = 0.f;
    float S4 = 0.f, S5 = 0.f, S6 = 0.f, S7 = 0.f;
    uint Kk1 = ~0u, Kk2 = ~0u;

    __syncthreads();   // staging complete

    int lofs = lane * 8;
    const ushort* lp = sP + lofs;
    const float* lpn = sPn + lgr * 4;
    short8 pa0 = *(const short8*)lp;
    short8 pa1 = *(const short8*)(lp + 512);
    f32x4 pnC = *(const f32x4*)lpn;

#define SM(ACCR, S) S += __builtin_amdgcn_exp2f(-__builtin_amdgcn_sqrtf(ACCR));

#define AMIN(E0, E1, E2, E3, O0, O1, O2, O3, MA, MB, P, ACTB, K)           \
    {                                                                      \
        float s01 = MA ? E1 : E0;                                          \
        float s23 = MA ? E3 : E2;                                          \
        float sE = MB ? s23 : s01;                                         \
        float t01 = MA ? O1 : O0;                                          \
        float t23 = MA ? O3 : O2;                                          \
        float sO = MB ? t23 : t01;                                         \
        float sel = (P ? sO : sE) + ACTB;                                  \
        uint key = (__float_as_uint(sel) & 0xFFFFFFF8u) | it;              \
        K = key < K ? key : K;                                             \
    }

    for (uint it = 0; it < (uint)(kSubt / 2); ++it) {
        // EVEN subtile: C-init = c2*(pn+qn); MFMA output = scaled d2.
        f32x4 cE1 = pnC + qn1;
        f32x4 cE2 = pnC + qn2;
        f32x4 aE1 = __builtin_amdgcn_mfma_f32_16x16x32_bf16(pa0, b0h1, cE1, 0, 0, 0);
        aE1 = __builtin_amdgcn_mfma_f32_16x16x32_bf16(pa1, b1h1, aE1, 0, 0, 0);
        f32x4 aE2 = __builtin_amdgcn_mfma_f32_16x16x32_bf16(pa0, b0h2, cE2, 0, 0, 0);
        aE2 = __builtin_amdgcn_mfma_f32_16x16x32_bf16(pa1, b1h2, aE2, 0, 0, 0);
        lp += 1024; lpn += 16;
        pa0 = *(const short8*)lp;
        pa1 = *(const short8*)(lp + 512);
        pnC = *(const f32x4*)lpn;

        SM(aE1[0], S0) SM(aE1[1], S1) SM(aE1[2], S2) SM(aE1[3], S3)
        SM(aE2[0], S4) SM(aE2[1], S5) SM(aE2[2], S6) SM(aE2[3], S7)

        // ODD subtile
        f32x4 cO1 = pnC + qn1;
        f32x4 cO2 = pnC + qn2;
        f32x4 aO1 = __builtin_amdgcn_mfma_f32_16x16x32_bf16(pa0, b0h1, cO1, 0, 0, 0);
        aO1 = __builtin_amdgcn_mfma_f32_16x16x32_bf16(pa1, b1h1, aO1, 0, 0, 0);
        f32x4 aO2 = __builtin_amdgcn_mfma_f32_16x16x32_bf16(pa0, b0h2, cO2, 0, 0, 0);
        aO2 = __builtin_amdgcn_mfma_f32_16x16x32_bf16(pa1, b1h2, aO2, 0, 0, 0);
        lp += 1024; lpn += 16;
        pa0 = *(const short8*)lp;
        pa1 = *(const short8*)(lp + 512);
        pnC = *(const f32x4*)lpn;

        SM(aO1[0], S0) SM(aO1[1], S1) SM(aO1[2], S2) SM(aO1[3], S3)
        SM(aO2[0], S4) SM(aO2[1], S5) SM(aO2[2], S6) SM(aO2[3], S7)

        AMIN(aE1[0], aE1[1], aE1[2], aE1[3], aO1[0], aO1[1], aO1[2], aO1[3],
             m1a, m1b, p1, actb1, Kk1)
        AMIN(aE2[0], aE2[1], aE2[2], aE2[3], aO2[0], aO2[1], aO2[2], aO2[3],
             m2a, m2b, p2, actb2, Kk2)
    }
#undef SM
#undef AMIN

    float Ss1 = (S0 + S1) + (S2 + S3);
    float Ss2 = (S4 + S5) + (S6 + S7);
#pragma unroll
    for (int off = 16; off <= 32; off <<= 1) {
        Ss1 += __shfl_xor(Ss1, off);
        uint ok = __shfl_xor(Kk1, off);
        Kk1 = ok < Kk1 ? ok : Kk1;
        Ss2 += __shfl_xor(Ss2, off);
        uint ok2 = __shfl_xor(Kk2, off);
        Kk2 = ok2 < Kk2 ? ok2 : Kk2;
    }
    if (lane < 16) {
        size_t o1 = (size_t)split * kQ + q1;
        ws[OP_S2 + o1] = Ss1;
        ((uint*)ws)[OP_PB + o1] = Kk1;
        size_t o2 = (size_t)split * kQ + q2;
        ws[OP_S2 + o2] = Ss2;
        ((uint*)ws)[OP_PB + o2] = Kk2;
    }

    // ---- fused finalize: last split-wave for this tile merges (release/acquire).
    __threadfence();
    int done = 0;
    if (lane == 0) done = atomicAdd((int*)ws + OP_QTK + qt, 1);
    done = __shfl(done, 0);
    if (done == kSplit - 1 && lane < 16) {
        __threadfence();  // acquire: see other splits' partial stores
        float lsum, csum;
        {
            float S = 0.f; uint best = ~0u; int ksel = 0;
#pragma unroll
            for (int k = 0; k < kSplit; ++k) {
                size_t o = (size_t)k * kQ + q1;
                S += ws[OP_S2 + o];
                uint kk = ((const uint*)ws)[OP_PB + o];
                if (kk < best) { best = kk; ksel = k; }
            }
            int it2 = (int)(best & 7u);
            int besti = ksel * kCPS + (2 * it2 + ((qsec1 >> 4) & 1)) * 16
                      + ((qsec1 & 15) >> 2) * 4 + (qsec1 & 3);
            lsum = ws[OP_DT + q1] + logf(S);
            csum = (besti == ((const int*)ws)[OP_TC + q1]) ? 1.f : 0.f;
        }
        {
            float S = 0.f; uint best = ~0u; int ksel = 0;
#pragma unroll
            for (int k = 0; k < kSplit; ++k) {
                size_t o = (size_t)k * kQ + q2;
                S += ws[OP_S2 + o];
                uint kk = ((const uint*)ws)[OP_PB + o];
                if (kk < best) { best = kk; ksel = k; }
            }
            int it2 = (int)(best & 7u);
            int besti = ksel * kCPS + (2 * it2 + ((qsec2 >> 4) & 1)) * 16
                      + ((qsec2 & 15) >> 2) * 4 + (qsec2 & 3);
            lsum += ws[OP_DT + q2] + logf(S);
            csum += (besti == ((const int*)ws)[OP_TC + q2]) ? 1.f : 0.f;
        }
#pragma unroll
        for (int off = 1; off < 16; off <<= 1) {
            lsum += __shfl_xor(lsum, off);
            csum += __shfl_xor(csum, off);
        }
        if (lane == 0) {
            atomicAdd(ws + OP_ACC, lsum);
            atomicAdd(ws + OP_ACC + 1, csum);
            __threadfence();
            int old = atomicAdd((int*)ws + OP_TICK, 1);
            if (old == kTPS - 1) {
                __threadfence();
                float L = atomicAdd(ws + OP_ACC, 0.f);
                float A = atomicAdd(ws + OP_ACC + 1, 0.f);
                out[0] = L / (float)kQ;
                out[1] = A / (float)kQ;
            }
        }
    }
}

extern "C" void kernel_launch(void* const* d_in, const int* in_sizes, int n_in,
                              void* d_out, int out_size, void* d_ws, size_t ws_size,
                              hipStream_t stream) {
    const float* x = (const float*)d_in[0];
    const int* target = (const int*)d_in[1];
    float* out = (float*)d_out;
    float* ws = (float*)d_ws;

    k_prepsec<<<544, 256, 0, stream>>>(x, ws);
    k_qprep<<<kQ / 16 / 4, 256, 0, stream>>>(x, target, ws);
    k_main<<<kBlkPerSplit * kSplit, 512, 0, stream>>>(x, ws, out);
}

// Round 16
// 58.582 us; speedup vs baseline: 5.4108x; 5.4108x over previous
//
#include <hip/hip_runtime.h>
#include <hip/hip_bf16.h>

constexpr int kC   = 2048;
constexpr int kNS  = 5;
constexpr int kNQ  = 25;
constexpr int kPER = 30;
constexpr int kD   = 64;
constexpr int kS   = 32;
constexpr int kQ   = kC * kNQ;              // 51200
constexpr int kSplit = 8;
constexpr int kSubt  = (kC / kSplit) / 16;  // 16 subtiles per task
constexpr int kCPS   = kC / kSplit;         // 256 classes per split
constexpr int kTPS   = kQ / 32;             // 1600 query tiles (32 q each)
constexpr int kBlkPerSplit = kTPS / 8;      // 200 blocks per split (8 waves/block)
constexpr int kFinBlocks = kQ / 256;        // 200

constexpr float kLOG2E = 1.44269504088896340736f;
constexpr float kC2    = kLOG2E * kLOG2E;
constexpr float kNEG2C = -2.0f * kC2;
constexpr float kBIG   = 1e30f;

// Workspace (float offsets), ~4.7 MB total.
constexpr size_t OP_PROT = 0;                              // [C*D] f32 protos
constexpr size_t OP_PSWZ = OP_PROT + (size_t)kC * kD;      // [C*D bf16] swizzled frags, scaled by -2*c2
constexpr size_t OP_PN   = OP_PSWZ + (size_t)kC * kD / 2;  // [C] |p|^2 raw
constexpr size_t OP_PNC2 = OP_PN + kC;                     // [C] |p|^2 * kC2
constexpr size_t OP_SSWH = OP_PNC2 + kC;                   // [S*D bf16] sector frags hi
constexpr size_t OP_SSWL = OP_SSWH + (size_t)kS * kD / 2;  // [S*D bf16] sector frags lo
constexpr size_t OP_SN   = OP_SSWL + (size_t)kS * kD / 2;  // [S] |s|^2
constexpr size_t OP_QNC  = OP_SN + kS;                     // [Q] qn * kC2
constexpr size_t OP_QSEC = OP_QNC + kQ;                    // [Q] int query sector
constexpr size_t OP_DT   = OP_QSEC + kQ;                   // [Q] exact fp32 dtrue
constexpr size_t OP_TC   = OP_DT + kQ;                     // [Q] int true class
constexpr size_t OP_S2   = OP_TC + kQ;                     // [Split*Q] partial sum exp
constexpr size_t OP_PB   = OP_S2 + (size_t)kSplit * kQ;    // [Split*Q] uint argmin keys
constexpr size_t OP_ACC  = OP_PB + (size_t)kSplit * kQ;    // [2]
constexpr size_t OP_TICK = OP_ACC + 2;                     // [1] int ticket

typedef __attribute__((ext_vector_type(8))) short short8;
typedef __attribute__((ext_vector_type(4))) float f32x4;

__device__ inline ushort f2bf(float f) {
    __hip_bfloat16 h = __float2bfloat16(f);
    return *reinterpret_cast<ushort*>(&h);
}
__device__ inline float bf2f(ushort u) {
    uint v = ((uint)u) << 16;
    return __int_as_float((int)v);
}
__device__ inline short8 pack_hi(float4 a, float4 b) {
    short8 r;
    r[0] = (short)f2bf(a.x); r[1] = (short)f2bf(a.y);
    r[2] = (short)f2bf(a.z); r[3] = (short)f2bf(a.w);
    r[4] = (short)f2bf(b.x); r[5] = (short)f2bf(b.y);
    r[6] = (short)f2bf(b.z); r[7] = (short)f2bf(b.w);
    return r;
}
__device__ inline void packhl(float4 a, float4 b, short8& hi, short8& lo) {
    float v[8] = {a.x, a.y, a.z, a.w, b.x, b.y, b.z, b.w};
#pragma unroll
    for (int i = 0; i < 8; ++i) {
        ushort h = f2bf(v[i]);
        hi[i] = (short)h;
        lo[i] = (short)f2bf(v[i] - bf2f(h));
    }
}

// K1: fused prep (verified absmax 0.0). Blocks [0,512): class protos
// (4 classes/block): f32 proto + swizzled bf16 frag scaled by -2*c2 + |p|^2
// (+ zero accumulators). Blocks [512,544): sector protos read x directly
// (csec[c]=c%32 episode structure), summation order identical to the
// two-kernel path.
__global__ __launch_bounds__(256) void k_prepsec(const float* __restrict__ x,
                                                 float* __restrict__ ws) {
    int t = threadIdx.x;
    if (blockIdx.x < 512) {
        int c = blockIdx.x * 4 + (t >> 6);
        int d = t & 63;
        const float* base = x + (size_t)c * kPER * kD + d;
        float p = 0.f;
#pragma unroll
        for (int s = 0; s < kNS; ++s) p += base[s * kD];
        p *= (1.f / kNS);
        ws[OP_PROT + (size_t)c * kD + d] = p;
        ((ushort*)(ws + OP_PSWZ))[((c >> 4) * 1024) + ((d >> 3) * 128) + ((c & 15) * 8) + (d & 7)] =
            f2bf(p * kNEG2C);
        float sq = p * p;
        for (int off = 32; off; off >>= 1) sq += __shfl_down(sq, off);
        if (d == 0) {
            ws[OP_PN + c] = sq;
            ws[OP_PNC2 + c] = sq * kC2;
        }
        if (blockIdx.x == 0 && t == 0) {
            ws[OP_ACC] = 0.f;
            ws[OP_ACC + 1] = 0.f;
            ((int*)ws)[OP_TICK] = 0;
        }
    } else {
        __shared__ float sAcc[4][kD];
        int s = blockIdx.x - 512;
        int w = t >> 6, d = t & 63;
        float acc = 0.f;
#pragma unroll
        for (int j = 0; j < 16; ++j) {
            int c = s + 32 * (w + 4 * j);
            const float* base = x + (size_t)c * kPER * kD + d;
            float p = 0.f;
#pragma unroll
            for (int i = 0; i < kNS; ++i) p += base[i * kD];
            p *= (1.f / kNS);
            acc += p;
        }
        sAcc[w][d] = acc;
        __syncthreads();
        if (w == 0) {
            float sp = (sAcc[0][d] + sAcc[1][d] + sAcc[2][d] + sAcc[3][d]) * (1.f / 64.f);
            ushort h = f2bf(sp);
            ushort l = f2bf(sp - bf2f(h));
            int idx = ((s >> 4) * 1024) + ((d >> 3) * 128) + ((s & 15) * 8) + (d & 7);
            ((ushort*)(ws + OP_SSWH))[idx] = h;
            ((ushort*)(ws + OP_SSWL))[idx] = l;
            float sq = sp * sp;
            for (int off = 32; off; off >>= 1) sq += __shfl_down(sq, off);
            if (d == 0) ws[OP_SN + s] = sq;
        }
    }
}

// K2: per-query qn*kC2, sector assignment (double-bf16 MFMA), exact fp32 dtrue, tc.
// Kept separate from k_main (merging under a min-waves pin spilled in R13;
// fusing the finalize with device fences serialized the machine in R15).
__global__ __launch_bounds__(256) void k_qprep(const float* __restrict__ x,
                                               const int* __restrict__ target,
                                               float* __restrict__ ws) {
    int t = threadIdx.x;
    int w = t >> 6, lane = t & 63;
    int lrow = lane & 15, lgr = lane >> 4;
    int qt = blockIdx.x * 4 + w;
    int q = qt * 16 + lrow;
    int row = (q / kNQ) * kPER + kNS + q % kNQ;
    const float* qr = x + (size_t)row * kD + lgr * 8;
    float4 qa0 = *(const float4*)qr,        qa1 = *(const float4*)(qr + 4);
    float4 qb0 = *(const float4*)(qr + 32), qb1 = *(const float4*)(qr + 36);

    float qn = qa0.x*qa0.x + qa0.y*qa0.y + qa0.z*qa0.z + qa0.w*qa0.w
             + qa1.x*qa1.x + qa1.y*qa1.y + qa1.z*qa1.z + qa1.w*qa1.w
             + qb0.x*qb0.x + qb0.y*qb0.y + qb0.z*qb0.z + qb0.w*qb0.w
             + qb1.x*qb1.x + qb1.y*qb1.y + qb1.z*qb1.z + qb1.w*qb1.w;
    qn += __shfl_xor(qn, 16);
    qn += __shfl_xor(qn, 32);

    int tc = target[row];
    const float* pr = ws + OP_PROT + (size_t)tc * kD + lgr * 8;
    float4 p00 = *(const float4*)pr,        p01 = *(const float4*)(pr + 4);
    float4 p10 = *(const float4*)(pr + 32), p11 = *(const float4*)(pr + 36);
    float dot = qa0.x*p00.x + qa0.y*p00.y + qa0.z*p00.z + qa0.w*p00.w
              + qa1.x*p01.x + qa1.y*p01.y + qa1.z*p01.z + qa1.w*p01.w
              + qb0.x*p10.x + qb0.y*p10.y + qb0.z*p10.z + qb0.w*p10.w
              + qb1.x*p11.x + qb1.y*p11.y + qb1.z*p11.z + qb1.w*p11.w;
    dot += __shfl_xor(dot, 16);
    dot += __shfl_xor(dot, 32);
    float dtrue = sqrtf(fmaxf(qn + ws[OP_PN + tc] - 2.f * dot, 0.f));

    short8 b0h, b0l, b1h, b1l;
    packhl(qa0, qa1, b0h, b0l);
    packhl(qb0, qb1, b1h, b1l);

    const ushort* ssh = (const ushort*)(ws + OP_SSWH);
    const ushort* ssl = (const ushort*)(ws + OP_SSWL);
    float bestS = INFINITY;
    int qsec = 0;
#pragma unroll
    for (int st = 0; st < 2; ++st) {
        short8 sh0 = *(const short8*)(ssh + st * 1024 + lane * 8);
        short8 sh1 = *(const short8*)(ssh + st * 1024 + 512 + lane * 8);
        short8 sl0 = *(const short8*)(ssl + st * 1024 + lane * 8);
        short8 sl1 = *(const short8*)(ssl + st * 1024 + 512 + lane * 8);
        f32x4 dh = {0.f, 0.f, 0.f, 0.f};
        dh = __builtin_amdgcn_mfma_f32_16x16x32_bf16(sh0, b0h, dh, 0, 0, 0);
        dh = __builtin_amdgcn_mfma_f32_16x16x32_bf16(sh1, b1h, dh, 0, 0, 0);
        dh = __builtin_amdgcn_mfma_f32_16x16x32_bf16(sh0, b0l, dh, 0, 0, 0);
        dh = __builtin_amdgcn_mfma_f32_16x16x32_bf16(sh1, b1l, dh, 0, 0, 0);
        dh = __builtin_amdgcn_mfma_f32_16x16x32_bf16(sl0, b0h, dh, 0, 0, 0);
        dh = __builtin_amdgcn_mfma_f32_16x16x32_bf16(sl1, b1h, dh, 0, 0, 0);
        f32x4 sn4 = *(const f32x4*)(ws + OP_SN + st * 16 + lgr * 4);
#pragma unroll
        for (int r2 = 0; r2 < 4; ++r2) {
            float score = fmaf(dh[r2], -2.f, sn4[r2]);
            int idx = st * 16 + lgr * 4 + r2;
            if (score < bestS) { bestS = score; qsec = idx; }
        }
    }
#pragma unroll
    for (int off = 16; off <= 32; off <<= 1) {
        float ob = __shfl_xor(bestS, off);
        int oi = __shfl_xor(qsec, off);
        if (ob < bestS || (ob == bestS && oi < qsec)) { bestS = ob; qsec = oi; }
    }
    if (lane < 16) {
        ws[OP_QNC + q] = qn * kC2;
        ((int*)ws)[OP_QSEC + q] = qsec;
        ws[OP_DT + q] = dtrue;
        ((int*)ws)[OP_TC + q] = tc;
    }
}

// K3: hot kernel (R12/R14 version — no min-waves pin; 52 VGPR, LDS gives
// 4 blk/CU -> 8 waves/SIMD = occupancy cap). MFMA C-init = c2*(pn+qn); A
// pre-scaled by -2*c2 -> MFMA output IS the scaled d2. Per pair: sqrt + exp2
// + add. No fences (R15 lesson: per-wave device fences serialize the chip).
__global__ __launch_bounds__(512) void k_main(const float* __restrict__ x,
                                              float* __restrict__ ws) {
    __shared__ ushort sP[kSubt * 1024 + 1024];  // 34KB + pad for prefetch overrun
    __shared__ float sPn[kSubt * 16 + 16];

    int t = threadIdx.x;
    int w = t >> 6, lane = t & 63;
    int lrow = lane & 15, lgr = lane >> 4;
    int split = blockIdx.x / kBlkPerSplit;          // 8 waves share this split
    int qt = (blockIdx.x % kBlkPerSplit) * 8 + w;
    int qbase = qt * 32;
    int q1 = qbase + lrow, q2 = qbase + 16 + lrow;

    // Stage protos: 2048 float4 = 32KB, 4 per thread, coalesced.
    {
        const float4* gsrc = (const float4*)((const ushort*)(ws + OP_PSWZ) + (size_t)split * kSubt * 1024);
        float4* ldst = (float4*)sP;
#pragma unroll
        for (int j = 0; j < 4; ++j) ldst[t + j * 512] = gsrc[t + j * 512];
        if (t < kCPS) sPn[t] = ws[OP_PNC2 + split * kCPS + t];
    }

    int row1 = (q1 / kNQ) * kPER + kNS + q1 % kNQ;
    int row2 = (q2 / kNQ) * kPER + kNS + q2 % kNQ;
    const float* qr1 = x + (size_t)row1 * kD + lgr * 8;
    const float* qr2 = x + (size_t)row2 * kD + lgr * 8;
    float4 a10 = *(const float4*)qr1,        a11 = *(const float4*)(qr1 + 4);
    float4 a12 = *(const float4*)(qr1 + 32), a13 = *(const float4*)(qr1 + 36);
    float4 a20 = *(const float4*)qr2,        a21 = *(const float4*)(qr2 + 4);
    float4 a22 = *(const float4*)(qr2 + 32), a23 = *(const float4*)(qr2 + 36);
    short8 b0h1 = pack_hi(a10, a11), b1h1 = pack_hi(a12, a13);
    short8 b0h2 = pack_hi(a20, a21), b1h2 = pack_hi(a22, a23);

    float qn1 = ws[OP_QNC + q1];          // pre-scaled by kC2
    float qn2 = ws[OP_QNC + q2];
    int qsec1 = ((const int*)ws)[OP_QSEC + q1];
    int qsec2 = ((const int*)ws)[OP_QSEC + q2];

    bool m1a = (qsec1 & 1), m1b = (qsec1 >> 1) & 1, p1 = (qsec1 >> 4) & 1;
    float actb1 = (((qsec1 & 15) >> 2) == lgr) ? 0.f : kBIG;
    bool m2a = (qsec2 & 1), m2b = (qsec2 >> 1) & 1, p2 = (qsec2 >> 4) & 1;
    float actb2 = (((qsec2 & 15) >> 2) == lgr) ? 0.f : kBIG;

    float S0 = 0.f, S1 = 0.f, S2 = 0.f, S3 = 0.f;
    float S4 = 0.f, S5 = 0.f, S6 = 0.f, S7 = 0.f;
    uint Kk1 = ~0u, Kk2 = ~0u;

    __syncthreads();   // staging complete

    int lofs = lane * 8;
    const ushort* lp = sP + lofs;
    const float* lpn = sPn + lgr * 4;
    short8 pa0 = *(const short8*)lp;
    short8 pa1 = *(const short8*)(lp + 512);
    f32x4 pnC = *(const f32x4*)lpn;

#define SM(ACCR, S) S += __builtin_amdgcn_exp2f(-__builtin_amdgcn_sqrtf(ACCR));

#define AMIN(E0, E1, E2, E3, O0, O1, O2, O3, MA, MB, P, ACTB, K)           \
    {                                                                      \
        float s01 = MA ? E1 : E0;                                          \
        float s23 = MA ? E3 : E2;                                          \
        float sE = MB ? s23 : s01;                                         \
        float t01 = MA ? O1 : O0;                                          \
        float t23 = MA ? O3 : O2;                                          \
        float sO = MB ? t23 : t01;                                         \
        float sel = (P ? sO : sE) + ACTB;                                  \
        uint key = (__float_as_uint(sel) & 0xFFFFFFF8u) | it;              \
        K = key < K ? key : K;                                             \
    }

    for (uint it = 0; it < (uint)(kSubt / 2); ++it) {
        // EVEN subtile: C-init = c2*(pn+qn); MFMA output = scaled d2.
        f32x4 cE1 = pnC + qn1;
        f32x4 cE2 = pnC + qn2;
        f32x4 aE1 = __builtin_amdgcn_mfma_f32_16x16x32_bf16(pa0, b0h1, cE1, 0, 0, 0);
        aE1 = __builtin_amdgcn_mfma_f32_16x16x32_bf16(pa1, b1h1, aE1, 0, 0, 0);
        f32x4 aE2 = __builtin_amdgcn_mfma_f32_16x16x32_bf16(pa0, b0h2, cE2, 0, 0, 0);
        aE2 = __builtin_amdgcn_mfma_f32_16x16x32_bf16(pa1, b1h2, aE2, 0, 0, 0);
        lp += 1024; lpn += 16;
        pa0 = *(const short8*)lp;
        pa1 = *(const short8*)(lp + 512);
        pnC = *(const f32x4*)lpn;

        SM(aE1[0], S0) SM(aE1[1], S1) SM(aE1[2], S2) SM(aE1[3], S3)
        SM(aE2[0], S4) SM(aE2[1], S5) SM(aE2[2], S6) SM(aE2[3], S7)

        // ODD subtile
        f32x4 cO1 = pnC + qn1;
        f32x4 cO2 = pnC + qn2;
        f32x4 aO1 = __builtin_amdgcn_mfma_f32_16x16x32_bf16(pa0, b0h1, cO1, 0, 0, 0);
        aO1 = __builtin_amdgcn_mfma_f32_16x16x32_bf16(pa1, b1h1, aO1, 0, 0, 0);
        f32x4 aO2 = __builtin_amdgcn_mfma_f32_16x16x32_bf16(pa0, b0h2, cO2, 0, 0, 0);
        aO2 = __builtin_amdgcn_mfma_f32_16x16x32_bf16(pa1, b1h2, aO2, 0, 0, 0);
        lp += 1024; lpn += 16;
        pa0 = *(const short8*)lp;
        pa1 = *(const short8*)(lp + 512);
        pnC = *(const f32x4*)lpn;

        SM(aO1[0], S0) SM(aO1[1], S1) SM(aO1[2], S2) SM(aO1[3], S3)
        SM(aO2[0], S4) SM(aO2[1], S5) SM(aO2[2], S6) SM(aO2[3], S7)

        AMIN(aE1[0], aE1[1], aE1[2], aE1[3], aO1[0], aO1[1], aO1[2], aO1[3],
             m1a, m1b, p1, actb1, Kk1)
        AMIN(aE2[0], aE2[1], aE2[2], aE2[3], aO2[0], aO2[1], aO2[2], aO2[3],
             m2a, m2b, p2, actb2, Kk2)
    }
#undef SM
#undef AMIN

    float Ss1 = (S0 + S1) + (S2 + S3);
    float Ss2 = (S4 + S5) + (S6 + S7);
#pragma unroll
    for (int off = 16; off <= 32; off <<= 1) {
        Ss1 += __shfl_xor(Ss1, off);
        uint ok = __shfl_xor(Kk1, off);
        Kk1 = ok < Kk1 ? ok : Kk1;
        Ss2 += __shfl_xor(Ss2, off);
        uint ok2 = __shfl_xor(Kk2, off);
        Kk2 = ok2 < Kk2 ? ok2 : Kk2;
    }
    if (lane < 16) {
        size_t o1 = (size_t)split * kQ + q1;
        ws[OP_S2 + o1] = Ss1;
        ((uint*)ws)[OP_PB + o1] = Kk1;
        size_t o2 = (size_t)split * kQ + q2;
        ws[OP_S2 + o2] = Ss2;
        ((uint*)ws)[OP_PB + o2] = Kk2;
    }
}

// K4: merge splits (min key, ascending split keeps first class), decode besti,
// loss/acc reduce, ticketed final write. No x reads (R12/R14 version).
__global__ __launch_bounds__(256) void k_fin(float* __restrict__ ws,
                                             float* __restrict__ out) {
    int t = threadIdx.x;
    int q = blockIdx.x * 256 + t;

    float S = 0.f;
    uint best = ~0u;
    int ksel = 0;
#pragma unroll
    for (int k = 0; k < kSplit; ++k) {
        size_t o = (size_t)k * kQ + q;
        S += ws[OP_S2 + o];
        uint kk = ((const uint*)ws)[OP_PB + o];
        if (kk < best) { best = kk; ksel = k; }
    }
    int qsec = ((const int*)ws)[OP_QSEC + q];
    int it = (int)(best & 7u);
    int besti = ksel * kCPS + (2 * it + ((qsec >> 4) & 1)) * 16
              + ((qsec & 15) >> 2) * 4 + (qsec & 3);

    float loss = ws[OP_DT + q] + logf(S);
    float corr = (besti == ((const int*)ws)[OP_TC + q]) ? 1.f : 0.f;

    __shared__ float rl[256], rc[256];
    rl[t] = loss;
    rc[t] = corr;
    __syncthreads();
    for (int off = 128; off; off >>= 1) {
        if (t < off) { rl[t] += rl[t + off]; rc[t] += rc[t + off]; }
        __syncthreads();
    }
    if (t == 0) {
        atomicAdd(ws + OP_ACC, rl[0]);
        atomicAdd(ws + OP_ACC + 1, rc[0]);
        __threadfence();
        int old = atomicAdd((int*)ws + OP_TICK, 1);
        if (old == kFinBlocks - 1) {
            __threadfence();
            float L = atomicAdd(ws + OP_ACC, 0.f);
            float A = atomicAdd(ws + OP_ACC + 1, 0.f);
            out[0] = L / (float)kQ;
            out[1] = A / (float)kQ;
        }
    }
}

extern "C" void kernel_launch(void* const* d_in, const int* in_sizes, int n_in,
                              void* d_out, int out_size, void* d_ws, size_t ws_size,
                              hipStream_t stream) {
    const float* x = (const float*)d_in[0];
    const int* target = (const int*)d_in[1];
    float* out = (float*)d_out;
    float* ws = (float*)d_ws;

    k_prepsec<<<544, 256, 0, stream>>>(x, ws);
    k_qprep<<<kQ / 16 / 4, 256, 0, stream>>>(x, target, ws);
    k_main<<<kBlkPerSplit * kSplit, 512, 0, stream>>>(x, ws);
    k_fin<<<kFinBlocks, 256, 0, stream>>>(ws, out);
}